// Round 15
// baseline (57.529 us; speedup 1.0000x reference)
//
#include <hip/hip_runtime.h>
#include <hip/hip_bf16.h>

typedef short bf16x8 __attribute__((ext_vector_type(8)));
typedef float f32x16 __attribute__((ext_vector_type(16)));

#define NB 8
#define NPTS 8192
#define NSET (NB * NPTS)

static __device__ __forceinline__ short bfbits(float x) {
    __hip_bfloat16 h = __float2bfloat16(x);  // RNE
    return *reinterpret_cast<short*>(&h);
}
static __device__ __forceinline__ float bfval(float x) {
    __hip_bfloat16 h = __float2bfloat16(x);
    return __bfloat162float(h);
}

// Per point, emit K=16 bf16 row-features (A, linear) and col-features (B,
// FRAGMENT ORDER per 32-pt tile: tile*1024B; lane reads its frag at
// tile*1024 + lane*16) so that dot(A_t, B_p) = |t|^2+|p|^2-2t.p (hi/lo split).
__global__ __launch_bounds__(256) void pack2_kernel(
    const float* __restrict__ target, const float* __restrict__ pred,
    short* __restrict__ tA, short* __restrict__ tB,
    short* __restrict__ pA, short* __restrict__ pB) {
    int gi = blockIdx.x * 256 + threadIdx.x;
    int second = gi >= NSET;
    int i = second ? gi - NSET : gi;
    const float* pts = second ? pred : target;
    short* A = second ? pA : tA;
    short* B = second ? pB : tB;

    float x = pts[3 * i + 0], y = pts[3 * i + 1], z = pts[3 * i + 2];
    float n2 = x * x + y * y + z * z;

    float xh = bfval(x), yh = bfval(y), zh = bfval(z), nh = bfval(n2);
    short xhb = bfbits(x), yhb = bfbits(y), zhb = bfbits(z), nhb = bfbits(n2);
    short xlb = bfbits(x - xh), ylb = bfbits(y - yh), zlb = bfbits(z - zh), nlb = bfbits(n2 - nh);
    short one = bfbits(1.0f);
    short mxh = bfbits(-2.0f * xh), myh = bfbits(-2.0f * yh), mzh = bfbits(-2.0f * zh);
    short mxl = bfbits(-2.0f * __bfloat162float(*(__hip_bfloat16*)&xlb));
    short myl = bfbits(-2.0f * __bfloat162float(*(__hip_bfloat16*)&ylb));
    short mzl = bfbits(-2.0f * __bfloat162float(*(__hip_bfloat16*)&zlb));

    // A k=0..15: [1,1,n2h,n2l, xh,xh,xl, yh,yh,yl, zh,zh,zl, 0,0,0]
    bf16x8 a0, a1, b0, b1;
    a0[0] = one; a0[1] = one; a0[2] = nhb; a0[3] = nlb;
    a0[4] = xhb; a0[5] = xhb; a0[6] = xlb; a0[7] = yhb;
    a1[0] = yhb; a1[1] = ylb; a1[2] = zhb; a1[3] = zhb;
    a1[4] = zlb; a1[5] = 0;   a1[6] = 0;   a1[7] = 0;
    // B k=0..15: [n2h,n2l,1,1, -2xh,-2xl,-2xh, -2yh,-2yl,-2yh, -2zh,-2zl,-2zh, 0,0,0]
    b0[0] = nhb; b0[1] = nlb; b0[2] = one; b0[3] = one;
    b0[4] = mxh; b0[5] = mxl; b0[6] = mxh; b0[7] = myh;
    b1[0] = myl; b1[1] = myh; b1[2] = mzh; b1[3] = mzl;
    b1[4] = mzh; b1[5] = 0;   b1[6] = 0;   b1[7] = 0;

    *reinterpret_cast<bf16x8*>(&A[(size_t)i * 16])     = a0;
    *reinterpret_cast<bf16x8*>(&A[(size_t)i * 16 + 8]) = a1;

    int bb = i >> 13;                 // batch
    int pi = i & (NPTS - 1);
    int tile = pi >> 5, l = pi & 31;
    short* Bp = B + (size_t)bb * NPTS * 16 + tile * 512;
    *reinterpret_cast<bf16x8*>(Bp + l * 8)       = b0;   // khalf 0 (lane h=0)
    *reinterpret_cast<bf16x8*>(Bp + 256 + l * 8) = b1;   // khalf 1 (lane h=1)
}

// lane-merge: combine two row-registers across lane-pairs (xor m).
#define MERGE(dst, u, v, m) {                       \
    float _own = (lane & (m)) ? (v) : (u);          \
    float _sel = (lane & (m)) ? (u) : (v);          \
    dst = fminf(_own, __shfl_xor(_sel, (m))); }

// merge one 64-row group (two 16-reg acc sets) -> 1 rowmin per lane, store.
#define EPI(A0, A1, ROWOFF) {                                                  \
    _Pragma("unroll") for (int k = 0; k < 8; ++k) { MERGE(A0[k], A0[2*k], A0[2*k+1], 1); } \
    _Pragma("unroll") for (int k = 0; k < 8; ++k) { MERGE(A1[k], A1[2*k], A1[2*k+1], 1); } \
    _Pragma("unroll") for (int k = 0; k < 4; ++k) { MERGE(A0[k], A0[2*k], A0[2*k+1], 2); } \
    _Pragma("unroll") for (int k = 0; k < 4; ++k) { MERGE(A1[k], A1[2*k], A1[2*k+1], 2); } \
    _Pragma("unroll") for (int k = 0; k < 2; ++k) { MERGE(A0[k], A0[2*k], A0[2*k+1], 4); } \
    _Pragma("unroll") for (int k = 0; k < 2; ++k) { MERGE(A1[k], A1[2*k], A1[2*k+1], 4); } \
    MERGE(A0[0], A0[0], A0[1], 8);                                             \
    MERGE(A1[0], A1[0], A1[1], 8);                                             \
    float fin;                                                                 \
    MERGE(fin, A0[0], A1[0], 16);                                              \
    int row = (lane & 3) + 4 * ((lane >> 5) & 1) + 8 * ((lane >> 2) & 1)       \
            + 16 * ((lane >> 3) & 1) + 32 * ((lane >> 4) & 1);                 \
    rowmin[((size_t)(pass * 4 + colq)) * NSET + b * NPTS + row0 + (ROWOFF) + row] = fin; }

// Fast-math flags (nnan/nsz) for this kernel only: legalizes the backend's
// fminf(a, fminf(b,c)) -> v_min3_f32 combine. All values finite, so
// semantics are unchanged. (r14's hand-asm min3 corrupted results -- the
// compiler must own MFMA->VALU hazard handling.)
#pragma float_control(push)
#pragma float_control(precise, off)

// R=4 row-frags per wave (128 rows) x 2048-col quarter (32 pair-iters).
// Grid 1024 = dir x 8b x 16 rowgrp(512) x 4 colq.
__global__ __launch_bounds__(256, 3) void chamfer_mfma_kernel(
    const short* __restrict__ targA, const short* __restrict__ targB,
    const short* __restrict__ predA, const short* __restrict__ predB,
    float* __restrict__ rowmin)   // [2 dir][4 colq][NSET]
{
    const int bid  = blockIdx.x;
    const int pass = bid >> 9;
    const int b    = (bid >> 6) & 7;
    const int rowgrp = (bid >> 2) & 15;
    const int colq   = bid & 3;
    const int wave = threadIdx.x >> 6;
    const int lane = threadIdx.x & 63;
    const int l31  = lane & 31, h = lane >> 5;

    const short* Af = pass ? predA : targA;
    const short* Bf = pass ? targB : predB;

    const int row0 = rowgrp * 512 + wave * 128;
    const short* abase = Af + ((size_t)(b * NPTS + row0 + l31)) * 16 + h * 8;
    bf16x8 a0 = *reinterpret_cast<const bf16x8*>(abase);               // rows +0..31
    bf16x8 a1 = *reinterpret_cast<const bf16x8*>(abase + 1 * 32 * 16);
    bf16x8 a2 = *reinterpret_cast<const bf16x8*>(abase + 2 * 32 * 16);
    bf16x8 a3 = *reinterpret_cast<const bf16x8*>(abase + 3 * 32 * 16);  // +96..127

    const char* bbase = (const char*)Bf + (size_t)b * NPTS * 32
                      + (size_t)colq * 2048 * 32;   // 64KB frag-ordered quarter

    float acc0[16], acc1[16], acc2[16], acc3[16];
#pragma unroll
    for (int r = 0; r < 16; ++r) {
        acc0[r] = 3.4e38f; acc1[r] = 3.4e38f;
        acc2[r] = 3.4e38f; acc3[r] = 3.4e38f;
    }

    const f32x16 z = {0.f,0.f,0.f,0.f, 0.f,0.f,0.f,0.f, 0.f,0.f,0.f,0.f, 0.f,0.f,0.f,0.f};

#define LDT(t) (*reinterpret_cast<const bf16x8*>(bbase + (size_t)(t) * 1024 + lane * 16))
// fold: inner fminf(ca,cb) independent of acc (off the acc chain); with
// fast flags the backend fuses the pair into one v_min3_f32.
#define STEP(acc, af) {                                                        \
    f32x16 ca = __builtin_amdgcn_mfma_f32_32x32x16_bf16(af, c0a, z, 0, 0, 0);  \
    f32x16 cb = __builtin_amdgcn_mfma_f32_32x32x16_bf16(af, c0b, z, 0, 0, 0);  \
    _Pragma("unroll") for (int r = 0; r < 16; ++r)                             \
        acc[r] = fminf(acc[r], fminf(ca[r], cb[r]));                           \
}

    bf16x8 c0a = LDT(0), c0b = LDT(1);   // current pair (depth-1 prefetch)

    for (int it = 0; it < 32; ++it) {
        int tp = (it < 31) ? (2 * it + 2) : 62;   // clamped (uniform scalar)
        bf16x8 n0 = LDT(tp);
        bf16x8 n1 = LDT(tp + 1);
        STEP(acc0, a0);
        STEP(acc1, a1);
        STEP(acc2, a2);
        STEP(acc3, a3);
        c0a = n0; c0b = n1;
    }
#undef STEP
#undef LDT

    EPI(acc0, acc1, 0);    // rows row0 +  0..63
    EPI(acc2, acc3, 64);   // rows row0 + 64..127
}

#pragma float_control(pop)

// min the four col-quarters, sum -> one partial per block (no atomics/init).
__global__ __launch_bounds__(256) void reduce_kernel(const float* __restrict__ rowmin,
                                                     float* __restrict__ partials) {
    const int stride = gridDim.x * 256;
    float v = 0.0f;
    for (int i = blockIdx.x * 256 + threadIdx.x; i < 2 * NSET; i += stride) {
        int d = i >> 16;   // NSET = 65536
        int r = i & (NSET - 1);
        const float* base = rowmin + (size_t)d * 4 * NSET + r;
        float m = fminf(fminf(base[0], base[NSET]),
                        fminf(base[2 * (size_t)NSET], base[3 * (size_t)NSET]));
        v += m;
    }
#pragma unroll
    for (int o = 32; o > 0; o >>= 1) v += __shfl_xor(v, o);
    __shared__ float wpart[4];
    if ((threadIdx.x & 63) == 0) wpart[threadIdx.x >> 6] = v;
    __syncthreads();
    if (threadIdx.x == 0)
        partials[blockIdx.x] = wpart[0] + wpart[1] + wpart[2] + wpart[3];
}

__global__ __launch_bounds__(128) void final_kernel(const float* __restrict__ partials,
                                                    float* __restrict__ out) {
    __shared__ float wpart[2];
    float v = partials[threadIdx.x];
#pragma unroll
    for (int o = 32; o > 0; o >>= 1) v += __shfl_xor(v, o);
    if ((threadIdx.x & 63) == 0) wpart[threadIdx.x >> 6] = v;
    __syncthreads();
    if (threadIdx.x == 0)
        out[0] = (wpart[0] + wpart[1]) * (1.0f / (float)NSET);
}

extern "C" void kernel_launch(void* const* d_in, const int* in_sizes, int n_in,
                              void* d_out, int out_size, void* d_ws, size_t ws_size,
                              hipStream_t stream) {
    const float* pred   = (const float*)d_in[0];   // [8,8192,3]
    const float* target = (const float*)d_in[1];   // [8,8192,3]
    float* out = (float*)d_out;

    char* ws = (char*)d_ws;
    float* rowmin   = (float*)ws;                       // 8*NSET floats = 2MB
    float* partials = rowmin + (size_t)8 * NSET;        // 128 floats
    short* tA = (short*)(ws + (size_t)8 * NSET * 4 + 4096);  // each 2 MB
    short* tB = tA + (size_t)NSET * 16;
    short* pA = tB + (size_t)NSET * 16;
    short* pB = pA + (size_t)NSET * 16;

    pack2_kernel<<<2 * NSET / 256, 256, 0, stream>>>(target, pred, tA, tB, pA, pB);

    chamfer_mfma_kernel<<<1024, 256, 0, stream>>>(tA, tB, pA, pB, rowmin);

    reduce_kernel<<<128, 256, 0, stream>>>(rowmin, partials);
    final_kernel<<<1, 128, 0, stream>>>(partials, out);
}

// Round 16
// 54.689 us; speedup vs baseline: 1.0519x; 1.0519x over previous
//
#include <hip/hip_runtime.h>
#include <hip/hip_bf16.h>

typedef short bf16x8 __attribute__((ext_vector_type(8)));
typedef float f32x16 __attribute__((ext_vector_type(16)));

#define NB 8
#define NPTS 8192
#define NSET (NB * NPTS)

static __device__ __forceinline__ short bfbits(float x) {
    __hip_bfloat16 h = __float2bfloat16(x);  // RNE
    return *reinterpret_cast<short*>(&h);
}
static __device__ __forceinline__ float bfval(float x) {
    __hip_bfloat16 h = __float2bfloat16(x);
    return __bfloat162float(h);
}

// Per point, emit K=16 bf16 row-features (A, linear) and col-features (B,
// FRAGMENT ORDER per 32-pt tile: tile*1024B; lane reads its frag at
// tile*1024 + lane*16) so that dot(A_t, B_p) = |t|^2+|p|^2-2t.p (hi/lo split).
__global__ __launch_bounds__(256) void pack2_kernel(
    const float* __restrict__ target, const float* __restrict__ pred,
    short* __restrict__ tA, short* __restrict__ tB,
    short* __restrict__ pA, short* __restrict__ pB) {
    int gi = blockIdx.x * 256 + threadIdx.x;
    int second = gi >= NSET;
    int i = second ? gi - NSET : gi;
    const float* pts = second ? pred : target;
    short* A = second ? pA : tA;
    short* B = second ? pB : tB;

    float x = pts[3 * i + 0], y = pts[3 * i + 1], z = pts[3 * i + 2];
    float n2 = x * x + y * y + z * z;

    float xh = bfval(x), yh = bfval(y), zh = bfval(z), nh = bfval(n2);
    short xhb = bfbits(x), yhb = bfbits(y), zhb = bfbits(z), nhb = bfbits(n2);
    short xlb = bfbits(x - xh), ylb = bfbits(y - yh), zlb = bfbits(z - zh), nlb = bfbits(n2 - nh);
    short one = bfbits(1.0f);
    short mxh = bfbits(-2.0f * xh), myh = bfbits(-2.0f * yh), mzh = bfbits(-2.0f * zh);
    short mxl = bfbits(-2.0f * __bfloat162float(*(__hip_bfloat16*)&xlb));
    short myl = bfbits(-2.0f * __bfloat162float(*(__hip_bfloat16*)&ylb));
    short mzl = bfbits(-2.0f * __bfloat162float(*(__hip_bfloat16*)&zlb));

    // A k=0..15: [1,1,n2h,n2l, xh,xh,xl, yh,yh,yl, zh,zh,zl, 0,0,0]
    bf16x8 a0, a1, b0, b1;
    a0[0] = one; a0[1] = one; a0[2] = nhb; a0[3] = nlb;
    a0[4] = xhb; a0[5] = xhb; a0[6] = xlb; a0[7] = yhb;
    a1[0] = yhb; a1[1] = ylb; a1[2] = zhb; a1[3] = zhb;
    a1[4] = zlb; a1[5] = 0;   a1[6] = 0;   a1[7] = 0;
    // B k=0..15: [n2h,n2l,1,1, -2xh,-2xl,-2xh, -2yh,-2yl,-2yh, -2zh,-2zl,-2zh, 0,0,0]
    b0[0] = nhb; b0[1] = nlb; b0[2] = one; b0[3] = one;
    b0[4] = mxh; b0[5] = mxl; b0[6] = mxh; b0[7] = myh;
    b1[0] = myl; b1[1] = myh; b1[2] = mzh; b1[3] = mzl;
    b1[4] = mzh; b1[5] = 0;   b1[6] = 0;   b1[7] = 0;

    *reinterpret_cast<bf16x8*>(&A[(size_t)i * 16])     = a0;
    *reinterpret_cast<bf16x8*>(&A[(size_t)i * 16 + 8]) = a1;

    int bb = i >> 13;                 // batch
    int pi = i & (NPTS - 1);
    int tile = pi >> 5, l = pi & 31;
    short* Bp = B + (size_t)bb * NPTS * 16 + tile * 512;
    *reinterpret_cast<bf16x8*>(Bp + l * 8)       = b0;   // khalf 0 (lane h=0)
    *reinterpret_cast<bf16x8*>(Bp + 256 + l * 8) = b1;   // khalf 1 (lane h=1)
}

// lane-merge: combine two row-registers across lane-pairs (xor m).
#define MERGE(dst, u, v, m) {                       \
    float _own = (lane & (m)) ? (v) : (u);          \
    float _sel = (lane & (m)) ? (u) : (v);          \
    dst = fminf(_own, __shfl_xor(_sel, (m))); }

// merge one 64-row group (two 16-reg acc sets) -> 1 rowmin per lane, store.
#define EPI(A0, A1, ROWOFF) {                                                  \
    _Pragma("unroll") for (int k = 0; k < 8; ++k) { MERGE(A0[k], A0[2*k], A0[2*k+1], 1); } \
    _Pragma("unroll") for (int k = 0; k < 8; ++k) { MERGE(A1[k], A1[2*k], A1[2*k+1], 1); } \
    _Pragma("unroll") for (int k = 0; k < 4; ++k) { MERGE(A0[k], A0[2*k], A0[2*k+1], 2); } \
    _Pragma("unroll") for (int k = 0; k < 4; ++k) { MERGE(A1[k], A1[2*k], A1[2*k+1], 2); } \
    _Pragma("unroll") for (int k = 0; k < 2; ++k) { MERGE(A0[k], A0[2*k], A0[2*k+1], 4); } \
    _Pragma("unroll") for (int k = 0; k < 2; ++k) { MERGE(A1[k], A1[2*k], A1[2*k+1], 4); } \
    MERGE(A0[0], A0[0], A0[1], 8);                                             \
    MERGE(A1[0], A1[0], A1[1], 8);                                             \
    float fin;                                                                 \
    MERGE(fin, A0[0], A1[0], 16);                                              \
    int row = (lane & 3) + 4 * ((lane >> 5) & 1) + 8 * ((lane >> 2) & 1)       \
            + 16 * ((lane >> 3) & 1) + 32 * ((lane >> 4) & 1);                 \
    rowmin[((size_t)(pass * 4 + colq)) * NSET + b * NPTS + row0 + (ROWOFF) + row] = fin; }

// R=2 row-frags per wave (64 rows) x 2048-col quarter (32 pair-iters).
// Grid 2048 = dir x 8b x 32 rowgrp(256) x 4 colq -> 8 blocks/CU.
// SMALL register footprint is the point: acc 32 + a 8 + B 32 + C transient
// 32 + addr ~12 = ~124 unified regs <= the (256,4) cap of 128 -> 4 waves/SIMD
// actually resident (r12-r15's R=4 needed ~250 unified regs -> 2 waves/SIMD
// regardless of grid; arch-VGPR counter hid the AGPR half). Barrier-free.
__global__ __launch_bounds__(256, 4) void chamfer_mfma_kernel(
    const short* __restrict__ targA, const short* __restrict__ targB,
    const short* __restrict__ predA, const short* __restrict__ predB,
    float* __restrict__ rowmin)   // [2 dir][4 colq][NSET]
{
    const int bid  = blockIdx.x;
    const int pass = bid >> 10;
    const int b    = (bid >> 7) & 7;
    const int rowgrp = (bid >> 2) & 31;
    const int colq   = bid & 3;
    const int wave = threadIdx.x >> 6;
    const int lane = threadIdx.x & 63;
    const int l31  = lane & 31, h = lane >> 5;

    const short* Af = pass ? predA : targA;
    const short* Bf = pass ? targB : predB;

    const int row0 = rowgrp * 256 + wave * 64;
    const short* abase = Af + ((size_t)(b * NPTS + row0 + l31)) * 16 + h * 8;
    bf16x8 a0 = *reinterpret_cast<const bf16x8*>(abase);            // rows +0..31
    bf16x8 a1 = *reinterpret_cast<const bf16x8*>(abase + 32 * 16);  // rows +32..63

    const char* bbase = (const char*)Bf + (size_t)b * NPTS * 32
                      + (size_t)colq * 2048 * 32;   // 64KB frag-ordered quarter

    float acc0[16], acc1[16];
#pragma unroll
    for (int r = 0; r < 16; ++r) { acc0[r] = 3.4e38f; acc1[r] = 3.4e38f; }

    const f32x16 z = {0.f,0.f,0.f,0.f, 0.f,0.f,0.f,0.f, 0.f,0.f,0.f,0.f, 0.f,0.f,0.f,0.f};

#define LDT(t) (*reinterpret_cast<const bf16x8*>(bbase + (size_t)(t) * 1024 + lane * 16))
// pair-fold: inner fminf(ca,cb) independent of acc chain.
#define STEP(acc, af) {                                                        \
    f32x16 ca = __builtin_amdgcn_mfma_f32_32x32x16_bf16(af, c0a, z, 0, 0, 0);  \
    f32x16 cb = __builtin_amdgcn_mfma_f32_32x32x16_bf16(af, c0b, z, 0, 0, 0);  \
    _Pragma("unroll") for (int r = 0; r < 16; ++r)                             \
        acc[r] = fminf(acc[r], fminf(ca[r], cb[r]));                           \
}

    bf16x8 c0a = LDT(0), c0b = LDT(1);   // current pair (depth-1 prefetch)

    for (int it = 0; it < 32; ++it) {
        int tp = (it < 31) ? (2 * it + 2) : 62;   // clamped (uniform scalar)
        bf16x8 n0 = LDT(tp);
        bf16x8 n1 = LDT(tp + 1);
        STEP(acc0, a0);
        STEP(acc1, a1);
        c0a = n0; c0b = n1;
    }
#undef STEP
#undef LDT

    EPI(acc0, acc1, 0);    // rows row0 + 0..63
}

// min the four col-quarters, sum -> one partial per block (no atomics/init).
__global__ __launch_bounds__(256) void reduce_kernel(const float* __restrict__ rowmin,
                                                     float* __restrict__ partials) {
    const int stride = gridDim.x * 256;
    float v = 0.0f;
    for (int i = blockIdx.x * 256 + threadIdx.x; i < 2 * NSET; i += stride) {
        int d = i >> 16;   // NSET = 65536
        int r = i & (NSET - 1);
        const float* base = rowmin + (size_t)d * 4 * NSET + r;
        float m = fminf(fminf(base[0], base[NSET]),
                        fminf(base[2 * (size_t)NSET], base[3 * (size_t)NSET]));
        v += m;
    }
#pragma unroll
    for (int o = 32; o > 0; o >>= 1) v += __shfl_xor(v, o);
    __shared__ float wpart[4];
    if ((threadIdx.x & 63) == 0) wpart[threadIdx.x >> 6] = v;
    __syncthreads();
    if (threadIdx.x == 0)
        partials[blockIdx.x] = wpart[0] + wpart[1] + wpart[2] + wpart[3];
}

__global__ __launch_bounds__(128) void final_kernel(const float* __restrict__ partials,
                                                    float* __restrict__ out) {
    __shared__ float wpart[2];
    float v = partials[threadIdx.x];
#pragma unroll
    for (int o = 32; o > 0; o >>= 1) v += __shfl_xor(v, o);
    if ((threadIdx.x & 63) == 0) wpart[threadIdx.x >> 6] = v;
    __syncthreads();
    if (threadIdx.x == 0)
        out[0] = (wpart[0] + wpart[1]) * (1.0f / (float)NSET);
}

extern "C" void kernel_launch(void* const* d_in, const int* in_sizes, int n_in,
                              void* d_out, int out_size, void* d_ws, size_t ws_size,
                              hipStream_t stream) {
    const float* pred   = (const float*)d_in[0];   // [8,8192,3]
    const float* target = (const float*)d_in[1];   // [8,8192,3]
    float* out = (float*)d_out;

    char* ws = (char*)d_ws;
    float* rowmin   = (float*)ws;                       // 8*NSET floats = 2MB
    float* partials = rowmin + (size_t)8 * NSET;        // 128 floats
    short* tA = (short*)(ws + (size_t)8 * NSET * 4 + 4096);  // each 2 MB
    short* tB = tA + (size_t)NSET * 16;
    short* pA = tB + (size_t)NSET * 16;
    short* pB = pA + (size_t)NSET * 16;

    pack2_kernel<<<2 * NSET / 256, 256, 0, stream>>>(target, pred, tA, tB, pA, pB);

    chamfer_mfma_kernel<<<2048, 256, 0, stream>>>(tA, tB, pA, pB, rowmin);

    reduce_kernel<<<128, 256, 0, stream>>>(rowmin, partials);
    final_kernel<<<1, 128, 0, stream>>>(partials, out);
}